// Round 4
// baseline (233.373 us; speedup 1.0000x reference)
//
#include <hip/hip_runtime.h>

// Depthwise 3x3 conv (diagonal-masked dense conv), fp32.
// x: (32, 256, 64, 64). One block per (n,c) plane, NO LDS, NO barriers.
// Each thread computes a 4x4 tile (4 consecutive rows x one float4) and
// loads its 6 input row-float4s straight from global (independent,
// concurrently outstanding). Horizontal halos via lane shuffles (DPP),
// row halos via predicated-to-zero loads. Non-temporal stores.

#define C_CH 256
#define H_SP 64
#define W_SP 64
#define PLANE (H_SP * W_SP)      // 4096 floats

typedef float nfloat4 __attribute__((ext_vector_type(4))); // native vec for NT store

__global__ __launch_bounds__(256) void dwconv3x3_kernel(
    const float* __restrict__ x,
    const float* __restrict__ Wfull,
    float* __restrict__ out)
{
    const int p = blockIdx.x;              // plane index [0, 8192)
    const int c = p & (C_CH - 1);
    const float4* __restrict__ xv = (const float4*)(x + (size_t)p * PLANE);
    nfloat4* __restrict__ ov = (nfloat4*)(out + (size_t)p * PLANE);

    // 9 diagonal weights (block-uniform scalar loads)
    const float* __restrict__ wp = Wfull + (size_t)c * (C_CH + 1) * 9;
    const float w00 = wp[0], w01 = wp[1], w02 = wp[2];
    const float w10 = wp[3], w11 = wp[4], w12 = wp[5];
    const float w20 = wp[6], w21 = wp[7], w22 = wp[8];

    const int t  = threadIdx.x;
    const int q  = t & 15;                 // float4 column [0,16)
    const int hb = (t >> 4) << 2;          // base output row: 0..60 step 4

    // 6 input rows (hb-1 .. hb+4), predicated to zero outside the plane.
    float4 v[6];
#pragma unroll
    for (int j = 0; j < 6; ++j) {
        const int hh = hb + j - 1;
        v[j] = (hh >= 0 && hh < H_SP) ? xv[hh * 16 + q]
                                      : make_float4(0.f, 0.f, 0.f, 0.f);
    }

    // Horizontal halo scalars from neighbor lanes (row groups are 16 lanes,
    // so lane+-1 stays inside the 64-lane wave; edges masked to zero).
    float lf[6], rt[6];
#pragma unroll
    for (int j = 0; j < 6; ++j) {
        const float l = __shfl_up(v[j].w, 1, 64);
        lf[j] = (q == 0) ? 0.f : l;
        const float r = __shfl_down(v[j].x, 1, 64);
        rt[j] = (q == 15) ? 0.f : r;
    }

    // 4 output rows, each a 3-tap vertical combination of the staged rows.
#pragma unroll
    for (int r = 0; r < 4; ++r) {
        float4 acc = make_float4(0.f, 0.f, 0.f, 0.f);
#pragma unroll
        for (int kh = 0; kh < 3; ++kh) {
            const int j = r + kh;
            float k0, k1, k2;
            if (kh == 0)      { k0 = w00; k1 = w01; k2 = w02; }
            else if (kh == 1) { k0 = w10; k1 = w11; k2 = w12; }
            else              { k0 = w20; k1 = w21; k2 = w22; }
            const float4 cv = v[j];
            acc.x = fmaf(lf[j], k0, fmaf(cv.x, k1, fmaf(cv.y, k2, acc.x)));
            acc.y = fmaf(cv.x, k0, fmaf(cv.y, k1, fmaf(cv.z, k2, acc.y)));
            acc.z = fmaf(cv.y, k0, fmaf(cv.z, k1, fmaf(cv.w, k2, acc.z)));
            acc.w = fmaf(cv.z, k0, fmaf(cv.w, k1, fmaf(rt[j], k2, acc.w)));
        }
        nfloat4 accv = { acc.x, acc.y, acc.z, acc.w };
        __builtin_nontemporal_store(accv, &ov[(hb + r) * 16 + q]);
    }
}

extern "C" void kernel_launch(void* const* d_in, const int* in_sizes, int n_in,
                              void* d_out, int out_size, void* d_ws, size_t ws_size,
                              hipStream_t stream) {
    const float* x = (const float*)d_in[0];
    const float* W = (const float*)d_in[1];
    float* out = (float*)d_out;

    const int n_planes = out_size / PLANE;  // 8192
    dwconv3x3_kernel<<<n_planes, 256, 0, stream>>>(x, W, out);
}